// Round 4
// baseline (584.187 us; speedup 1.0000x reference)
//
#include <hip/hip_runtime.h>
#include <math.h>

// Problem dims
#define Bq 16
#define Tq 2048
#define Dq 1024
#define Vq 640
#define NTOK (Bq*Tq)          // 32768
#define KT 32                 // K-tiles of 32 fp32 k each
#define BM 256
#define BN 128

// ws layout (bytes)
#define CBC_OFF  0UL                 // 32*5*16384 = 2621440
#define PACK_OFF 2621440UL           // NTOK*8 = 262144
#define ACC_OFF  2883584UL           // 8

typedef _Float16 half4 __attribute__((ext_vector_type(4)));
typedef _Float16 half8 __attribute__((ext_vector_type(8)));
typedef float    f32x16 __attribute__((ext_vector_type(16)));

// ---------------- K0: convert codebook fp32 -> tiled swizzled f16 hi/lo ----------------
// Per (k-tile t, panel p): 16KB block [r(128)][128B]; octet o (8 k): hi 16B at o*32,
// lo 16B at o*32+16; byte offsets XOR-swizzled with ((r&7)<<4).
__global__ __launch_bounds__(256) void k_convB(const float* __restrict__ cb,
                                               _Float16* __restrict__ cbc)
{
    const int t = blockIdx.x / 5, p = blockIdx.x % 5;
    const int tid = threadIdx.x;
    const int sr  = tid >> 3;          // row 0..31 (+32*s)
    const int skk = (tid & 7) * 4;     // k offset in tile
    const int so  = (tid & 7) >> 1;    // octet 0..3
    const int sh  = tid & 1;           // half-octet
    char* dst = (char*)cbc + (long)(t * 5 + p) * 16384;
    const int boff = sr * 128 + ((so * 32 + sh * 8) ^ ((sr & 7) << 4));
    const float* src = cb + (long)(p * 128 + sr) * Dq + t * 32 + skk;
#pragma unroll
    for (int s = 0; s < 4; ++s) {
        float4 f = *(const float4*)(src + (long)s * 32 * Dq);
        float ff[4] = {f.x, f.y, f.z, f.w};
        half4 hi, lo;
#pragma unroll
        for (int j = 0; j < 4; ++j) {
            _Float16 h = (_Float16)ff[j];
            hi[j] = h;
            lo[j] = (_Float16)(ff[j] - (float)h);
        }
        *(half4*)(dst + boff + s * 4096) = hi;
        *(half4*)(dst + (boff ^ 16) + s * 4096) = lo;
    }
}

// ---------------- K1: fused GEMM + gumbel-argmax ----------------
// logits = z @ codebook^T via split-f16 MFMA (4-term, fp32-exact to 2^-22 splits;
// one MFMA covers hi*hi+lo*lo via k-halves, second covers the cross terms).
// BM=256 x BN=128 tile, 4 waves (2x2), wave-tile 128x64 (m=4,n=2 frags of 32x32).
// Epilogue: per row, max/argmax of (acc + gumbel), combined globally via
// atomicMax on key = (ordered(m)<<32) | (639-col)  (lowest-col tie-break).
__global__ __launch_bounds__(256, 2) void k_gemm(const float* __restrict__ z,
                                                 const _Float16* __restrict__ cbc,
                                                 const float* __restrict__ gum,
                                                 unsigned long long* __restrict__ packed)
{
    __shared__ __align__(16) char smem[49152];
    char* AsB = smem;            // A tile [256][128B] swizzled
    char* BsB = smem + 32768;    // B tile [128][128B] swizzled

    const int tid  = threadIdx.x;
    const int lane = tid & 63;
    const int w    = tid >> 6;
    const int wm   = w >> 1, wn = w & 1;

    // XCD-aware swizzle (640 = 8*80, bijective)
    int bid = blockIdx.x;
    bid = (bid & 7) * 80 + (bid >> 3);
    const int  colblk = bid % 5;
    const long row0   = (long)(bid / 5) * BM;
    const int  col0   = colblk * BN;

    // A staging: one thread per row, full 32 phys k (128B) per K-tile.
    // Per ds_write_b128: 64 lanes = 64 rows, bank slot = ((r&7)<<4) -> 8 lanes
    // per 4-bank group = minimum cycles, conflict-free.
    const int a_row_st = tid * 128;
    const int a_sw     = (tid & 7) << 4;
    const float* zrow  = z + (row0 + tid) * (long)Dq;

    const char* cbb = (const char*)cbc;

    // fragment read constants
    const int l31 = lane & 31, lh = lane >> 5;
    const int swz = (l31 & 7) << 4;
    const int a_base0 = (wm * 128 +  0 + l31) * 128;
    const int a_base1 = (wm * 128 + 32 + l31) * 128;
    const int a_base2 = (wm * 128 + 64 + l31) * 128;
    const int a_base3 = (wm * 128 + 96 + l31) * 128;
    const int b_base0 = (wn * 64 + l31) * 128;
    const int b_base1 = b_base0 + 32 * 128;

    f32x16 acc[4][2] = {};

    for (int t = 0; t < KT; ++t) {
        // ---- stage B (pre-converted, pre-swizzled; linear 16KB copy) ----
        const char* bsrc = cbb + (long)(t * 5 + colblk) * 16384;
#pragma unroll
        for (int s = 0; s < 4; ++s) {
            half8 bv = *(const half8*)(bsrc + s * 4096 + tid * 16);
            *(half8*)(BsB + s * 4096 + tid * 16) = bv;
        }
        // ---- stage A: 32 fp32 -> hi/lo f16, in two 16-float chunks ----
        const float* zt = zrow + t * 32;
#pragma unroll
        for (int h = 0; h < 2; ++h) {
            float4 v0 = *(const float4*)(zt + h * 16 + 0);
            float4 v1 = *(const float4*)(zt + h * 16 + 4);
            float4 v2 = *(const float4*)(zt + h * 16 + 8);
            float4 v3 = *(const float4*)(zt + h * 16 + 12);
            float f[16] = {v0.x, v0.y, v0.z, v0.w, v1.x, v1.y, v1.z, v1.w,
                           v2.x, v2.y, v2.z, v2.w, v3.x, v3.y, v3.z, v3.w};
            half8 hi0, lo0, hi1, lo1;
#pragma unroll
            for (int j = 0; j < 8; ++j) {
                _Float16 a = (_Float16)f[j];
                hi0[j] = a; lo0[j] = (_Float16)(f[j] - (float)a);
                _Float16 b = (_Float16)f[j + 8];
                hi1[j] = b; lo1[j] = (_Float16)(f[j + 8] - (float)b);
            }
            const int b0 = h * 64;
            *(half8*)(AsB + a_row_st + ((b0 +  0) ^ a_sw)) = hi0;
            *(half8*)(AsB + a_row_st + ((b0 + 16) ^ a_sw)) = lo0;
            *(half8*)(AsB + a_row_st + ((b0 + 32) ^ a_sw)) = hi1;
            *(half8*)(AsB + a_row_st + ((b0 + 48) ^ a_sw)) = lo1;
        }
        __syncthreads();

        // ---- compute: 4 octets x {4 A-frags, 2 B-cols, 2 passes} = 64 MFMA ----
#pragma unroll
        for (int o = 0; o < 4; ++o) {
            const int ko = (o * 32 + lh * 16) ^ swz;
            half8 a0 = *(const half8*)(AsB + a_base0 + ko);
            half8 a1 = *(const half8*)(AsB + a_base1 + ko);
            half8 a2 = *(const half8*)(AsB + a_base2 + ko);
            half8 a3 = *(const half8*)(AsB + a_base3 + ko);
#pragma unroll
            for (int fn = 0; fn < 2; ++fn) {
                const int bb = (fn ? b_base1 : b_base0);
                half8 b  = *(const half8*)(BsB + bb + ko);
                half8 bx = *(const half8*)(BsB + bb + (ko ^ 16));
                acc[0][fn] = __builtin_amdgcn_mfma_f32_32x32x16_f16(a0, b,  acc[0][fn], 0, 0, 0);
                acc[1][fn] = __builtin_amdgcn_mfma_f32_32x32x16_f16(a1, b,  acc[1][fn], 0, 0, 0);
                acc[2][fn] = __builtin_amdgcn_mfma_f32_32x32x16_f16(a2, b,  acc[2][fn], 0, 0, 0);
                acc[3][fn] = __builtin_amdgcn_mfma_f32_32x32x16_f16(a3, b,  acc[3][fn], 0, 0, 0);
                acc[0][fn] = __builtin_amdgcn_mfma_f32_32x32x16_f16(a0, bx, acc[0][fn], 0, 0, 0);
                acc[1][fn] = __builtin_amdgcn_mfma_f32_32x32x16_f16(a1, bx, acc[1][fn], 0, 0, 0);
                acc[2][fn] = __builtin_amdgcn_mfma_f32_32x32x16_f16(a2, bx, acc[2][fn], 0, 0, 0);
                acc[3][fn] = __builtin_amdgcn_mfma_f32_32x32x16_f16(a3, bx, acc[3][fn], 0, 0, 0);
            }
        }
        __syncthreads();
    }

    // ---- epilogue: fused gumbel + row max/argmax + global atomicMax ----
    // C/D layout: col = lane&31, row = (reg&3) + 8*(reg>>2) + 4*(lane>>5).
    // shfl_xor offs 1..16 stay within each 32-lane half (same row group).
#pragma unroll
    for (int fm = 0; fm < 4; ++fm)
#pragma unroll
        for (int r = 0; r < 16; ++r) {
            const int rr = (r & 3) + 8 * (r >> 2) + 4 * lh;
            const long tok = row0 + wm * 128 + fm * 32 + rr;
            const int c0 = col0 + wn * 64 + l31;
            const int c1 = c0 + 32;
            float x0 = acc[fm][0][r] + gum[tok * Vq + c0];
            float x1 = acc[fm][1][r] + gum[tok * Vq + c1];
            float m; int c;
            if (x0 >= x1) { m = x0; c = c0; } else { m = x1; c = c1; }
#pragma unroll
            for (int off = 1; off <= 16; off <<= 1) {
                float om = __shfl_xor(m, off);
                int   oc = __shfl_xor(c, off);
                if (om > m || (om == m && oc < c)) { m = om; c = oc; }
            }
            if (l31 == 0) {
                unsigned int mb = __float_as_uint(m);
                mb = (mb & 0x80000000u) ? ~mb : (mb | 0x80000000u);
                const unsigned long long key =
                    ((unsigned long long)mb << 32) | (unsigned int)(Vq - 1 - c);
                atomicMax(packed + tok, key);
            }
        }
}

// ------------- K2: quantized[tok] = W_p[idx[tok]]  (val == 1.0 exactly) -------------
// Wave per token, 4 tokens/block.
__global__ __launch_bounds__(256) void k_gather(const float* __restrict__ Wp,
                                                const unsigned long long* __restrict__ packed,
                                                float* __restrict__ out)
{
    const int  lane = threadIdx.x & 63;
    const long tok  = (long)blockIdx.x * 4 + (threadIdx.x >> 6);
    const int  v    = (Vq - 1) - (int)(unsigned int)(packed[tok] & 0xffffffffu);
    const float4* src = (const float4*)(Wp + (long)v * Dq);
    float4*       dst = (float4*)(out + tok * Dq);
#pragma unroll
    for (int j = 0; j < 4; ++j) dst[lane + 64 * j] = src[lane + 64 * j];
}

// ------------- K3: entropy from per-row index counts (one wave per row t) -------------
__global__ __launch_bounds__(256) void k_entropy(const unsigned long long* __restrict__ packed,
                                                 double* __restrict__ accum)
{
    const int lane = threadIdx.x & 63;
    const int wid  = threadIdx.x >> 6;
    const int t    = blockIdx.x * 4 + wid;

    int col = 0x7fff0000 + lane;                       // no-match sentinel for lanes>=16
    if (lane < 16) {
        unsigned long long pk = packed[(long)lane * Tq + t];
        col = (Vq - 1) - (int)(unsigned int)(pk & 0xffffffffu);
    }
    int n = 0, first = 64;
#pragma unroll
    for (int j = 0; j < 16; ++j) {
        const int cj = __shfl(col, j);
        if (cj == col) { ++n; if (j < first) first = j; }
    }
    float c = 0.f;
    if (lane < 16 && first == lane) {
        const float avg = (float)n * 0.0625f;          // counts/16, exact in fp32
        c = -avg * logf(avg + 1e-10f);
    }
#pragma unroll
    for (int off = 1; off < 64; off <<= 1) c += __shfl_xor(c, off);
    __shared__ float red[4];
    if (lane == 0) red[wid] = c;
    __syncthreads();
    if (threadIdx.x == 0) atomicAdd(accum, (double)(red[0] + red[1] + red[2] + red[3]));
}

__global__ void k_final(const double* __restrict__ accum, float* __restrict__ out)
{
    out[0] = (float)(accum[0] / (double)Tq);
}

extern "C" void kernel_launch(void* const* d_in, const int* in_sizes, int n_in,
                              void* d_out, int out_size, void* d_ws, size_t ws_size,
                              hipStream_t stream)
{
    const float* z   = (const float*)d_in[0];
    const float* cb  = (const float*)d_in[1];
    const float* wp  = (const float*)d_in[2];
    const float* gum = (const float*)d_in[3];
    float* out = (float*)d_out;

    char* ws = (char*)d_ws;
    _Float16*           cbc    = (_Float16*)(ws + CBC_OFF);
    unsigned long long* packed = (unsigned long long*)(ws + PACK_OFF);
    double*             accum  = (double*)(ws + ACC_OFF);

    hipMemsetAsync(packed, 0, (size_t)NTOK * 8, stream);
    hipMemsetAsync(accum, 0, 8, stream);

    k_convB  <<<160, 256, 0, stream>>>(cb, cbc);
    k_gemm   <<<(NTOK / BM) * 5, 256, 0, stream>>>(z, cbc, gum, packed);
    k_gather <<<NTOK / 4, 256, 0, stream>>>(wp, packed, out);
    k_entropy<<<Tq / 4, 256, 0, stream>>>(packed, accum);
    k_final  <<<1, 1, 0, stream>>>(accum, out + (long)NTOK * Dq);
}